// Round 3
// baseline (179.319 us; speedup 1.0000x reference)
//
#include <hip/hip_runtime.h>
#include <hip/hip_bf16.h>

typedef unsigned short u16;
typedef __attribute__((ext_vector_type(4))) int   int4v;
typedef __attribute__((ext_vector_type(4))) unsigned int uint4v;
typedef __attribute__((ext_vector_type(4))) unsigned short ushort4v;
typedef __attribute__((ext_vector_type(4))) float floatx4;
typedef __attribute__((ext_vector_type(8))) short bf16x8;

#define LRELU_NS 0.01f
#define SK 264   // LDS k-stride (bf16): 256 + 8 pad, 16B-aligned rows

__device__ __forceinline__ float bitsToF(unsigned int b) {
    union { unsigned int u; float f; } v; v.u = b << 16; return v.f;
}
__device__ __forceinline__ float bfLo(unsigned int d) {
    union { unsigned int u; float f; } v; v.u = d << 16; return v.f;
}
__device__ __forceinline__ float bfHi(unsigned int d) {
    union { unsigned int u; float f; } v; v.u = d & 0xffff0000u; return v.f;
}
__device__ __forceinline__ u16 f2bf(float f) {
    __hip_bfloat16 h = __float2bfloat16(f);
    return *reinterpret_cast<u16*>(&h);
}
__device__ __forceinline__ float lrelu(float v) {
    return fmaxf(v, 0.f) + LRELU_NS * fminf(v, 0.f);
}
// dtype-adaptive element fetch (isF32 is block-uniform)
__device__ __forceinline__ u16 ldW(const void* p, int i, int isF32) {
    return isF32 ? f2bf(((const float*)p)[i]) : ((const u16*)p)[i];
}
__device__ __forceinline__ float ldF(const void* p, int i, int isF32) {
    return isF32 ? ((const float*)p)[i]
                 : bitsToF((unsigned int)((const u16*)p)[i]);
}

// ---------------------------------------------------------------------------
// Kernel 0: dtype probe. Samples even-index u16s of yhat.
// bf16 world: every sample is a bf16 of ~N(0,1) -> exponent in [96,160).
// fp32 world: samples are low mantissa halves -> uniform -> ~25% "sane".
// flag = 1 means fp32 inputs.
// ---------------------------------------------------------------------------
__global__ __launch_bounds__(256) void probe_kernel(
    const u16* __restrict__ y, int* __restrict__ flag)
{
    __shared__ int cnt;
    if (threadIdx.x == 0) cnt = 0;
    __syncthreads();
    u16 v = y[2 * threadIdx.x];
    int e = (v >> 7) & 0xFF;
    if (v == 0 || (e >= 96 && e < 160)) atomicAdd(&cnt, 1);
    __syncthreads();
    if (threadIdx.x == 0) *flag = (cnt < 192) ? 1 : 0;
}

// ---------------------------------------------------------------------------
// Kernel 1: pack weights to canonical bf16 + biases to canonical fp32.
// WallT[c][k], c in [0,1024): concat(Ws1, Wc1, Wb1[:256], Wb1[256:]) transposed.
// W2T[c][k],  c in [0,64): cols 0..39 = Ws2^T, 48..52 = Wc2^T, rest zero.
// biasF[1024]: [0]bs1 [256]bc1 [512]bb1 [768]bs2 [808]bc2 [816]bb2
// ---------------------------------------------------------------------------
__global__ __launch_bounds__(256) void pack_kernel(
    const int* __restrict__ flag,
    const void* __restrict__ Ws1, const void* __restrict__ Wc1,
    const void* __restrict__ Wb1, const void* __restrict__ Ws2,
    const void* __restrict__ Wc2,
    const void* __restrict__ bs1, const void* __restrict__ bc1,
    const void* __restrict__ bb1, const void* __restrict__ bs2,
    const void* __restrict__ bc2, const void* __restrict__ bb2,
    u16* __restrict__ WallT, u16* __restrict__ W2T, float* __restrict__ biasF)
{
    const int isF32 = *flag;
    int e = blockIdx.x * 256 + threadIdx.x;
    if (e < 262144) {
        int k = e >> 10, cg = e & 1023;
        u16 v;
        if (cg < 256)      v = ldW(Ws1, k * 256 + cg, isF32);
        else if (cg < 512) v = ldW(Wc1, k * 256 + (cg - 256), isF32);
        else if (cg < 768) v = ldW(Wb1, k * 256 + (cg - 512), isF32);
        else               v = ldW(Wb1, (k + 256) * 256 + (cg - 768), isF32);
        WallT[cg * 256 + k] = v;
    } else if (e < 278528) {
        int e2 = e - 262144;
        int c = e2 >> 8, k = e2 & 255;
        u16 v = 0;
        if (c < 40)                 v = ldW(Ws2, k * 40 + c, isF32);
        else if (c >= 48 && c < 53) v = ldW(Wc2, k * 5 + (c - 48), isF32);
        W2T[c * 256 + k] = v;
    } else {
        int idx = e - 278528;            // [0, 1024)
        float v = 0.f;
        if (idx < 256)       v = ldF(bs1, idx, isF32);
        else if (idx < 512)  v = ldF(bc1, idx - 256, isF32);
        else if (idx < 768)  v = ldF(bb1, idx - 512, isF32);
        else if (idx < 808)  v = ldF(bs2, idx - 768, isF32);
        else if (idx < 813)  v = ldF(bc2, idx - 808, isF32);
        else if (idx >= 816 && idx < 821) v = ldF(bb2, idx - 816, isF32);
        biasF[idx] = v;
    }
}

// ---------------------------------------------------------------------------
// Kernel 2: symbols + charges, fully fused.
// Per block: 128 atoms. Layer1 (MFMA, W panels streamed via LDS) -> H in LDS
// -> Layer2 (MFMA, W2T B-frags from global) -> out.
// LDS: Xs 67584 + Wb 16896 + Hb 67584 = 152064 B.
// ---------------------------------------------------------------------------
__global__ __launch_bounds__(256) void heads_kernel(
    const int* __restrict__ flag,
    const void* __restrict__ Xv, const u16* __restrict__ WallT,
    const u16* __restrict__ W2T, const float* __restrict__ biasF,
    void* __restrict__ outv)
{
    __shared__ u16 Xs[128 * SK];
    __shared__ u16 Wb[32 * SK];
    __shared__ u16 Hb[128 * SK];
    const int t = threadIdx.x;
    const int bm0 = blockIdx.x * 128;
    const int isF32 = *flag;

    if (isF32) {   // stage X tile [128][256] from fp32, cvt to bf16
        const floatx4* __restrict__ src = (const floatx4*)((const float*)Xv + bm0 * 256);
        #pragma unroll
        for (int it = 0; it < 32; ++it) {
            int cid = t + it * 256;            // 8192 chunks of 4 floats
            int row = cid >> 6, ch = cid & 63;
            floatx4 f = src[cid];
            ushort4v u;
            u[0] = f2bf(f[0]); u[1] = f2bf(f[1]); u[2] = f2bf(f[2]); u[3] = f2bf(f[3]);
            *(ushort4v*)&Xs[row * SK + ch * 4] = u;
        }
    } else {       // stage X tile from bf16
        const int4v* __restrict__ src = (const int4v*)((const u16*)Xv + bm0 * 256);
        #pragma unroll
        for (int it = 0; it < 16; ++it) {
            int cid = t + it * 256;            // 4096 chunks of 8 bf16
            int row = cid >> 5, ch = cid & 31;
            *(int4v*)&Xs[row * SK + ch * 8] = src[cid];
        }
    }

    const int w = t >> 6, l = t & 63;
    const int ml = l & 15, kq = l >> 4, r0 = kq * 4;

    for (int head = 0; head < 2; ++head) {
        // ---- layer 1: 8 panels of 32 H-columns ----
        for (int p = 0; p < 8; ++p) {
            __syncthreads();   // prev panel's Wb reads done / Xs visible (p=0)
            {
                const int4v* __restrict__ src =
                    (const int4v*)(WallT + (head * 256 + p * 32) * 256);
                #pragma unroll
                for (int it = 0; it < 4; ++it) {
                    int c2 = t + it * 256;
                    int row = c2 >> 5, ch = c2 & 31;
                    *(int4v*)&Wb[row * SK + ch * 8] = src[c2];
                }
            }
            __syncthreads();

            floatx4 acc[2][2] = {};
            #pragma unroll
            for (int ks = 0; ks < 8; ++ks) {
                const int k0 = ks * 32 + kq * 8;
                bf16x8 a[2], bf[2];
                a[0]  = *(const bf16x8*)&Xs[(w * 32 + ml) * SK + k0];
                a[1]  = *(const bf16x8*)&Xs[(w * 32 + 16 + ml) * SK + k0];
                bf[0] = *(const bf16x8*)&Wb[(ml) * SK + k0];
                bf[1] = *(const bf16x8*)&Wb[(16 + ml) * SK + k0];
                #pragma unroll
                for (int i = 0; i < 2; ++i)
                    #pragma unroll
                    for (int j = 0; j < 2; ++j)
                        acc[i][j] = __builtin_amdgcn_mfma_f32_16x16x32_bf16(
                            a[i], bf[j], acc[i][j], 0, 0, 0);
            }
            #pragma unroll
            for (int j = 0; j < 2; ++j) {
                const int hcol = p * 32 + j * 16 + ml;
                const float bias = biasF[head * 256 + hcol];  // bs1 | bc1
                #pragma unroll
                for (int i = 0; i < 2; ++i)
                    #pragma unroll
                    for (int r = 0; r < 4; ++r) {
                        const int row = w * 32 + i * 16 + r0 + r;
                        Hb[row * SK + hcol] = f2bf(lrelu(acc[i][j][r] + bias));
                    }
            }
        }
        __syncthreads();   // Hb complete

        // ---- layer 2: H[128,256] @ W2[256, 40|5] ----
        const int nct = (head == 0) ? 3 : 1;
        const int c0  = (head == 0) ? 0 : 48;
        floatx4 acc2[2][3] = {};
        #pragma unroll
        for (int ks = 0; ks < 8; ++ks) {
            const int k0 = ks * 32 + kq * 8;
            bf16x8 a[2];
            a[0] = *(const bf16x8*)&Hb[(w * 32 + ml) * SK + k0];
            a[1] = *(const bf16x8*)&Hb[(w * 32 + 16 + ml) * SK + k0];
            for (int j = 0; j < nct; ++j) {
                bf16x8 bf = *(const bf16x8*)&W2T[(c0 + j * 16 + ml) * 256 + k0];
                #pragma unroll
                for (int i = 0; i < 2; ++i)
                    acc2[i][j] = __builtin_amdgcn_mfma_f32_16x16x32_bf16(
                        a[i], bf, acc2[i][j], 0, 0, 0);
            }
        }
        for (int j = 0; j < nct; ++j) {
            const int col = j * 16 + ml;
            const int lim = (head == 0) ? 40 : 5;
            if (col < lim) {
                const float bias = biasF[(head == 0 ? 768 : 808) + col];
                #pragma unroll
                for (int i = 0; i < 2; ++i)
                    #pragma unroll
                    for (int r = 0; r < 4; ++r) {
                        const int row = bm0 + w * 32 + i * 16 + r0 + r;
                        const int o = (head == 0) ? row * 40 + col
                                                  : 409600 + row * 5 + col;
                        const float v = acc2[i][j][r] + bias;
                        if (isF32) ((float*)outv)[o] = v;
                        else ((__hip_bfloat16*)outv)[o] = __float2bfloat16(v);
                    }
            }
        }
    }
}

// ---------------------------------------------------------------------------
// Kernel 3: bonds, fully fused. One block per molecule.
// Layer1 (MFMA) -> P1/P2 bf16 in LDS -> pairwise VALU phase -> symmetrize.
// LDS: Xm 25344 + WbL 33792 + P1L 25344 + P2L 25344 + WbT 5360 + fbuf 32000
//    = 147184 B.
// ---------------------------------------------------------------------------
__global__ __launch_bounds__(256) void bonds_kernel(
    const int* __restrict__ flag,
    const void* __restrict__ Xv, const u16* __restrict__ WallT,
    const void* __restrict__ Wb2, const float* __restrict__ biasF,
    void* __restrict__ outv)
{
    __shared__ u16 Xm[48 * SK];
    __shared__ u16 WbL[64 * SK];
    __shared__ u16 P1L[48 * SK];
    __shared__ u16 P2L[48 * SK];
    __shared__ float WbT[5 * 268];
    __shared__ float fbuf[8000];
    const int t = threadIdx.x, b = blockIdx.x;
    const int isF32 = *flag;

    if (isF32) {   // stage X rows 0..39 (fp32 -> bf16), zero rows 40..47
        const floatx4* __restrict__ src = (const floatx4*)((const float*)Xv + b * 10240);
        #pragma unroll
        for (int it = 0; it < 10; ++it) {
            int cid = t + it * 256;            // 2560 chunks of 4 floats
            int row = cid >> 6, ch = cid & 63;
            floatx4 f = src[cid];
            ushort4v u;
            u[0] = f2bf(f[0]); u[1] = f2bf(f[1]); u[2] = f2bf(f[2]); u[3] = f2bf(f[3]);
            *(ushort4v*)&Xm[row * SK + ch * 4] = u;
        }
        for (int cid = t; cid < 512; cid += 256) {   // zero rows 40..47
            int row = 40 + (cid >> 6), ch = cid & 63;
            ushort4v z = {0, 0, 0, 0};
            *(ushort4v*)&Xm[row * SK + ch * 4] = z;
        }
    } else {
        const int4v* __restrict__ src = (const int4v*)((const u16*)Xv + b * 10240);
        #pragma unroll
        for (int it = 0; it < 6; ++it) {
            int cid = t + it * 256;
            int row = cid >> 5, ch = cid & 31;
            if (cid < 1280) *(int4v*)&Xm[row * SK + ch * 8] = src[cid];
            else if (cid < 1536) { int4v z = {0, 0, 0, 0}; *(int4v*)&Xm[row * SK + ch * 8] = z; }
        }
    }
    #pragma unroll
    for (int it = 0; it < 5; ++it) {      // Wb2 [256][5] -> WbT f32 [5][268]
        int e2 = t + it * 256;
        int k = e2 / 5, c = e2 - k * 5;
        WbT[c * 268 + k] = ldF(Wb2, e2, isF32);
    }

    const int w = t >> 6, l = t & 63;
    const int ml = l & 15, kq = l >> 4, r0 = kq * 4;

    // ---- layer 1: P = X @ Wb1 (+bb1 on P1 half), 8 panels of 64 cols ----
    for (int p = 0; p < 8; ++p) {
        __syncthreads();
        {
            const int4v* __restrict__ src =
                (const int4v*)(WallT + (512 + p * 64) * 256);
            #pragma unroll
            for (int it = 0; it < 8; ++it) {
                int c2 = t + it * 256;
                int row = c2 >> 5, ch = c2 & 31;
                *(int4v*)&WbL[row * SK + ch * 8] = src[c2];
            }
        }
        __syncthreads();

        floatx4 acc[3] = {};
        #pragma unroll
        for (int ks = 0; ks < 8; ++ks) {
            const int k0 = ks * 32 + kq * 8;
            bf16x8 bf = *(const bf16x8*)&WbL[(w * 16 + ml) * SK + k0];
            #pragma unroll
            for (int i = 0; i < 3; ++i) {
                bf16x8 a = *(const bf16x8*)&Xm[(i * 16 + ml) * SK + k0];
                acc[i] = __builtin_amdgcn_mfma_f32_16x16x32_bf16(a, bf, acc[i], 0, 0, 0);
            }
        }
        const int gc = p * 64 + w * 16 + ml;
        u16* dst = (gc < 256) ? P1L : P2L;
        const int col = gc & 255;
        const float bias = (gc < 256) ? biasF[512 + gc] : 0.f;   // bb1 on P1
        #pragma unroll
        for (int i = 0; i < 3; ++i)
            #pragma unroll
            for (int r = 0; r < 4; ++r)
                dst[(i * 16 + r0 + r) * SK + col] = f2bf(acc[i][r] + bias);
    }
    __syncthreads();

    // ---- phase 1: pairwise lrelu + dot with Wb2 ----
    float facc[2][4][5] = {};
    const int ia = (t / 20) * 2, ja = (t % 20) * 2;
    const int t1 = t + 256;
    const int ib = (t1 / 20) * 2, jb = (t1 % 20) * 2;
    const bool has2 = (t < 144);

    for (int kc = 0; kc < 32; ++kc) {
        const int k = kc * 8;
        float wv[5][8];
        #pragma unroll
        for (int c = 0; c < 5; ++c) {
            floatx4 lo = *(const floatx4*)&WbT[c * 268 + k];
            floatx4 hi = *(const floatx4*)&WbT[c * 268 + k + 4];
            wv[c][0] = lo[0]; wv[c][1] = lo[1]; wv[c][2] = lo[2]; wv[c][3] = lo[3];
            wv[c][4] = hi[0]; wv[c][5] = hi[1]; wv[c][6] = hi[2]; wv[c][7] = hi[3];
        }
        #pragma unroll
        for (int tl = 0; tl < 2; ++tl) {
            if (tl == 1 && !has2) break;
            const int i0 = tl ? ib : ia;
            const int j0 = tl ? jb : ja;
            uint4v A0 = *(const uint4v*)&P1L[(i0 + 0) * SK + k];
            uint4v A1 = *(const uint4v*)&P1L[(i0 + 1) * SK + k];
            uint4v B0 = *(const uint4v*)&P2L[(j0 + 0) * SK + k];
            uint4v B1 = *(const uint4v*)&P2L[(j0 + 1) * SK + k];
            float a0[8], a1[8], b0[8], b1[8];
            #pragma unroll
            for (int d = 0; d < 4; ++d) {
                a0[2*d] = bfLo(A0[d]); a0[2*d+1] = bfHi(A0[d]);
                a1[2*d] = bfLo(A1[d]); a1[2*d+1] = bfHi(A1[d]);
                b0[2*d] = bfLo(B0[d]); b0[2*d+1] = bfHi(B0[d]);
                b1[2*d] = bfLo(B1[d]); b1[2*d+1] = bfHi(B1[d]);
            }
            #pragma unroll
            for (int q = 0; q < 8; ++q) {
                const float av[2] = { a0[q], a1[q] };
                const float bv[2] = { b0[q], b1[q] };
                #pragma unroll
                for (int ii = 0; ii < 2; ++ii)
                    #pragma unroll
                    for (int jj = 0; jj < 2; ++jj) {
                        const float h = av[ii] + bv[jj];
                        const float pz = fmaxf(h, 0.f) + LRELU_NS * fminf(h, 0.f);
                        #pragma unroll
                        for (int c = 0; c < 5; ++c)
                            facc[tl][ii * 2 + jj][c] =
                                fmaf(pz, wv[c][q], facc[tl][ii * 2 + jj][c]);
                    }
            }
        }
    }

    #pragma unroll
    for (int ii = 0; ii < 2; ++ii)
        #pragma unroll
        for (int jj = 0; jj < 2; ++jj)
            #pragma unroll
            for (int c = 0; c < 5; ++c)
                fbuf[((ia + ii) * 40 + (ja + jj)) * 5 + c] = facc[0][ii * 2 + jj][c];
    if (has2) {
        #pragma unroll
        for (int ii = 0; ii < 2; ++ii)
            #pragma unroll
            for (int jj = 0; jj < 2; ++jj)
                #pragma unroll
                for (int c = 0; c < 5; ++c)
                    fbuf[((ib + ii) * 40 + (jb + jj)) * 5 + c] = facc[1][ii * 2 + jj][c];
    }
    __syncthreads();

    // ---- phase 2: symmetrize + 2*bb2 + store ----
    const int base = 460800 + b * 8000;
    for (int e = t; e < 8000; e += 256) {
        int pr = e / 5, c = e - pr * 5;
        int i = pr / 40, j = pr - (pr / 40) * 40;
        float v = fbuf[e] + fbuf[(j * 40 + i) * 5 + c] + 2.f * biasF[816 + c];
        if (isF32) ((float*)outv)[base + e] = v;
        else ((__hip_bfloat16*)outv)[base + e] = __float2bfloat16(v);
    }
}

// ---------------------------------------------------------------------------
extern "C" void kernel_launch(void* const* d_in, const int* in_sizes, int n_in,
                              void* d_out, int out_size, void* d_ws, size_t ws_size,
                              hipStream_t stream)
{
    const void* yhat = d_in[0];
    const void* Ws1  = d_in[1];
    const void* bs1  = d_in[2];
    const void* Ws2  = d_in[3];
    const void* bs2  = d_in[4];
    const void* Wc1  = d_in[5];
    const void* bc1  = d_in[6];
    const void* Wc2  = d_in[7];
    const void* bc2  = d_in[8];
    const void* Wb1  = d_in[9];
    const void* bb1  = d_in[10];
    const void* Wb2  = d_in[11];
    const void* bb2  = d_in[12];

    // workspace: 565248 bytes total
    char* wsb = (char*)d_ws;
    int*   flag  = (int*)(wsb + 0);
    float* biasF = (float*)(wsb + 4096);     // 1024 floats
    u16*   W2T   = (u16*)(wsb + 8192);       // 64*256 bf16  = 32768 B
    u16*   WallT = (u16*)(wsb + 40960);      // 1024*256 bf16 = 524288 B

    probe_kernel<<<1, 256, 0, stream>>>((const u16*)yhat, flag);
    pack_kernel<<<1092, 256, 0, stream>>>(flag, Ws1, Wc1, Wb1, Ws2, Wc2,
                                          bs1, bc1, bb1, bs2, bc2, bb2,
                                          WallT, W2T, biasF);
    heads_kernel<<<80, 256, 0, stream>>>(flag, yhat, WallT, W2T, biasF, d_out);
    bonds_kernel<<<256, 256, 0, stream>>>(flag, yhat, WallT, Wb2, biasF, d_out);
}

// Round 6
// 173.997 us; speedup vs baseline: 1.0306x; 1.0306x over previous
//
#include <hip/hip_runtime.h>
#include <hip/hip_bf16.h>

typedef unsigned short u16;
typedef __attribute__((ext_vector_type(4))) int   int4v;
typedef __attribute__((ext_vector_type(4))) unsigned int uint4v;
typedef __attribute__((ext_vector_type(4))) unsigned short ushort4v;
typedef __attribute__((ext_vector_type(4))) float floatx4;
typedef __attribute__((ext_vector_type(8))) short bf16x8;

#define LRELU_NS 0.01f
#define SK 264   // LDS k-stride (bf16): 256 + 8 pad, 16B-aligned rows

__device__ __forceinline__ float bitsToF(unsigned int b) {
    union { unsigned int u; float f; } v; v.u = b << 16; return v.f;
}
__device__ __forceinline__ float bfLo(unsigned int d) {
    union { unsigned int u; float f; } v; v.u = d << 16; return v.f;
}
__device__ __forceinline__ float bfHi(unsigned int d) {
    union { unsigned int u; float f; } v; v.u = d & 0xffff0000u; return v.f;
}
__device__ __forceinline__ u16 f2bf(float f) {
    __hip_bfloat16 h = __float2bfloat16(f);
    return *reinterpret_cast<u16*>(&h);
}
__device__ __forceinline__ float lrelu(float v) {
    return fmaxf(v, 0.f) + LRELU_NS * fminf(v, 0.f);
}
// dtype-adaptive element fetch (isF32 is block-uniform)
__device__ __forceinline__ u16 ldW(const void* p, int i, int isF32) {
    return isF32 ? f2bf(((const float*)p)[i]) : ((const u16*)p)[i];
}
__device__ __forceinline__ float ldF(const void* p, int i, int isF32) {
    return isF32 ? ((const float*)p)[i]
                 : bitsToF((unsigned int)((const u16*)p)[i]);
}

// ---------------------------------------------------------------------------
// Kernel 0: dtype probe. Samples even-index u16s of yhat.
// bf16 world: every sample is a bf16 of ~N(0,1) -> exponent in [96,160).
// fp32 world: samples are low mantissa halves -> uniform -> ~25% "sane".
// flag = 1 means fp32 inputs.
// ---------------------------------------------------------------------------
__global__ __launch_bounds__(256) void probe_kernel(
    const u16* __restrict__ y, int* __restrict__ flag)
{
    __shared__ int cnt;
    if (threadIdx.x == 0) cnt = 0;
    __syncthreads();
    u16 v = y[2 * threadIdx.x];
    int e = (v >> 7) & 0xFF;
    if (v == 0 || (e >= 96 && e < 160)) atomicAdd(&cnt, 1);
    __syncthreads();
    if (threadIdx.x == 0) *flag = (cnt < 192) ? 1 : 0;
}

// ---------------------------------------------------------------------------
// Kernel 1: pack weights to canonical bf16 + biases to canonical fp32.
// WallT[c][k], c in [0,1024): concat(Ws1, Wc1, Wb1[:256], Wb1[256:]) transposed.
// W2T[c][k],  c in [0,64): cols 0..39 = Ws2^T, 48..52 = Wc2^T, rest zero.
// biasF[1024]: [0]bs1 [256]bc1 [512]bb1 [768]bs2 [808]bc2 [816]bb2
// ---------------------------------------------------------------------------
__global__ __launch_bounds__(256) void pack_kernel(
    const int* __restrict__ flag,
    const void* __restrict__ Ws1, const void* __restrict__ Wc1,
    const void* __restrict__ Wb1, const void* __restrict__ Ws2,
    const void* __restrict__ Wc2,
    const void* __restrict__ bs1, const void* __restrict__ bc1,
    const void* __restrict__ bb1, const void* __restrict__ bs2,
    const void* __restrict__ bc2, const void* __restrict__ bb2,
    u16* __restrict__ WallT, u16* __restrict__ W2T, float* __restrict__ biasF)
{
    const int isF32 = *flag;
    int e = blockIdx.x * 256 + threadIdx.x;
    if (e < 262144) {
        int k = e >> 10, cg = e & 1023;
        u16 v;
        if (cg < 256)      v = ldW(Ws1, k * 256 + cg, isF32);
        else if (cg < 512) v = ldW(Wc1, k * 256 + (cg - 256), isF32);
        else if (cg < 768) v = ldW(Wb1, k * 256 + (cg - 512), isF32);
        else               v = ldW(Wb1, (k + 256) * 256 + (cg - 768), isF32);
        WallT[cg * 256 + k] = v;
    } else if (e < 278528) {
        int e2 = e - 262144;
        int c = e2 >> 8, k = e2 & 255;
        u16 v = 0;
        if (c < 40)                 v = ldW(Ws2, k * 40 + c, isF32);
        else if (c >= 48 && c < 53) v = ldW(Wc2, k * 5 + (c - 48), isF32);
        W2T[c * 256 + k] = v;
    } else {
        int idx = e - 278528;            // [0, 1024)
        float v = 0.f;
        if (idx < 256)       v = ldF(bs1, idx, isF32);
        else if (idx < 512)  v = ldF(bc1, idx - 256, isF32);
        else if (idx < 768)  v = ldF(bb1, idx - 512, isF32);
        else if (idx < 808)  v = ldF(bs2, idx - 768, isF32);
        else if (idx < 813)  v = ldF(bc2, idx - 808, isF32);
        else if (idx >= 816 && idx < 821) v = ldF(bb2, idx - 816, isF32);
        biasF[idx] = v;
    }
}

// ---------------------------------------------------------------------------
// Kernel 2: symbols + charges, fully fused.  (BYTE-IDENTICAL to round 3.)
// Per block: 128 atoms. Layer1 (MFMA, W panels streamed via LDS) -> H in LDS
// -> Layer2 (MFMA, W2T B-frags from global) -> out.
// LDS: Xs 67584 + Wb 16896 + Hb 67584 = 152064 B.
// ---------------------------------------------------------------------------
__global__ __launch_bounds__(256) void heads_kernel(
    const int* __restrict__ flag,
    const void* __restrict__ Xv, const u16* __restrict__ WallT,
    const u16* __restrict__ W2T, const float* __restrict__ biasF,
    void* __restrict__ outv)
{
    __shared__ u16 Xs[128 * SK];
    __shared__ u16 Wb[32 * SK];
    __shared__ u16 Hb[128 * SK];
    const int t = threadIdx.x;
    const int bm0 = blockIdx.x * 128;
    const int isF32 = *flag;

    if (isF32) {   // stage X tile [128][256] from fp32, cvt to bf16
        const floatx4* __restrict__ src = (const floatx4*)((const float*)Xv + bm0 * 256);
        #pragma unroll
        for (int it = 0; it < 32; ++it) {
            int cid = t + it * 256;            // 8192 chunks of 4 floats
            int row = cid >> 6, ch = cid & 63;
            floatx4 f = src[cid];
            ushort4v u;
            u[0] = f2bf(f[0]); u[1] = f2bf(f[1]); u[2] = f2bf(f[2]); u[3] = f2bf(f[3]);
            *(ushort4v*)&Xs[row * SK + ch * 4] = u;
        }
    } else {       // stage X tile from bf16
        const int4v* __restrict__ src = (const int4v*)((const u16*)Xv + bm0 * 256);
        #pragma unroll
        for (int it = 0; it < 16; ++it) {
            int cid = t + it * 256;            // 4096 chunks of 8 bf16
            int row = cid >> 5, ch = cid & 31;
            *(int4v*)&Xs[row * SK + ch * 8] = src[cid];
        }
    }

    const int w = t >> 6, l = t & 63;
    const int ml = l & 15, kq = l >> 4, r0 = kq * 4;

    for (int head = 0; head < 2; ++head) {
        // ---- layer 1: 8 panels of 32 H-columns ----
        for (int p = 0; p < 8; ++p) {
            __syncthreads();   // prev panel's Wb reads done / Xs visible (p=0)
            {
                const int4v* __restrict__ src =
                    (const int4v*)(WallT + (head * 256 + p * 32) * 256);
                #pragma unroll
                for (int it = 0; it < 4; ++it) {
                    int c2 = t + it * 256;
                    int row = c2 >> 5, ch = c2 & 31;
                    *(int4v*)&Wb[row * SK + ch * 8] = src[c2];
                }
            }
            __syncthreads();

            floatx4 acc[2][2] = {};
            #pragma unroll
            for (int ks = 0; ks < 8; ++ks) {
                const int k0 = ks * 32 + kq * 8;
                bf16x8 a[2], bf[2];
                a[0]  = *(const bf16x8*)&Xs[(w * 32 + ml) * SK + k0];
                a[1]  = *(const bf16x8*)&Xs[(w * 32 + 16 + ml) * SK + k0];
                bf[0] = *(const bf16x8*)&Wb[(ml) * SK + k0];
                bf[1] = *(const bf16x8*)&Wb[(16 + ml) * SK + k0];
                #pragma unroll
                for (int i = 0; i < 2; ++i)
                    #pragma unroll
                    for (int j = 0; j < 2; ++j)
                        acc[i][j] = __builtin_amdgcn_mfma_f32_16x16x32_bf16(
                            a[i], bf[j], acc[i][j], 0, 0, 0);
            }
            #pragma unroll
            for (int j = 0; j < 2; ++j) {
                const int hcol = p * 32 + j * 16 + ml;
                const float bias = biasF[head * 256 + hcol];  // bs1 | bc1
                #pragma unroll
                for (int i = 0; i < 2; ++i)
                    #pragma unroll
                    for (int r = 0; r < 4; ++r) {
                        const int row = w * 32 + i * 16 + r0 + r;
                        Hb[row * SK + hcol] = f2bf(lrelu(acc[i][j][r] + bias));
                    }
            }
        }
        __syncthreads();   // Hb complete

        // ---- layer 2: H[128,256] @ W2[256, 40|5] ----
        const int nct = (head == 0) ? 3 : 1;
        const int c0  = (head == 0) ? 0 : 48;
        floatx4 acc2[2][3] = {};
        #pragma unroll
        for (int ks = 0; ks < 8; ++ks) {
            const int k0 = ks * 32 + kq * 8;
            bf16x8 a[2];
            a[0] = *(const bf16x8*)&Hb[(w * 32 + ml) * SK + k0];
            a[1] = *(const bf16x8*)&Hb[(w * 32 + 16 + ml) * SK + k0];
            for (int j = 0; j < nct; ++j) {
                bf16x8 bf = *(const bf16x8*)&W2T[(c0 + j * 16 + ml) * 256 + k0];
                #pragma unroll
                for (int i = 0; i < 2; ++i)
                    acc2[i][j] = __builtin_amdgcn_mfma_f32_16x16x32_bf16(
                        a[i], bf, acc2[i][j], 0, 0, 0);
            }
        }
        for (int j = 0; j < nct; ++j) {
            const int col = j * 16 + ml;
            const int lim = (head == 0) ? 40 : 5;
            if (col < lim) {
                const float bias = biasF[(head == 0 ? 768 : 808) + col];
                #pragma unroll
                for (int i = 0; i < 2; ++i)
                    #pragma unroll
                    for (int r = 0; r < 4; ++r) {
                        const int row = bm0 + w * 32 + i * 16 + r0 + r;
                        const int o = (head == 0) ? row * 40 + col
                                                  : 409600 + row * 5 + col;
                        const float v = acc2[i][j][r] + bias;
                        if (isF32) ((float*)outv)[o] = v;
                        else ((__hip_bfloat16*)outv)[o] = __float2bfloat16(v);
                    }
            }
        }
    }
}

// ---------------------------------------------------------------------------
// Kernel 3: bonds — round-3 shell (staging, layer 1, phase 2 byte-identical);
// ONLY the pair phase is new: MFMA per (i, jtile) task with register-built
// A-frags, vs bf16 Wb2^T tile WsB (replaces fp32 WbT).
// LDS: Xm 25344 + WbL 33792 + P1L 25344 + P2L 25344 + WsB 8448 + fbuf 32000
//    = 150272 B.
// ---------------------------------------------------------------------------
__global__ __launch_bounds__(256) void bonds_kernel(
    const int* __restrict__ flag,
    const void* __restrict__ Xv, const u16* __restrict__ WallT,
    const void* __restrict__ Wb2, const float* __restrict__ biasF,
    void* __restrict__ outv)
{
    __shared__ u16 Xm[48 * SK];
    __shared__ u16 WbL[64 * SK];
    __shared__ u16 P1L[48 * SK];
    __shared__ u16 P2L[48 * SK];
    __shared__ u16 WsB[16 * 264];
    __shared__ float fbuf[8000];
    const int t = threadIdx.x, b = blockIdx.x;
    const int isF32 = *flag;

    if (isF32) {   // stage X rows 0..39 (fp32 -> bf16), zero rows 40..47
        const floatx4* __restrict__ src = (const floatx4*)((const float*)Xv + b * 10240);
        #pragma unroll
        for (int it = 0; it < 10; ++it) {
            int cid = t + it * 256;            // 2560 chunks of 4 floats
            int row = cid >> 6, ch = cid & 63;
            floatx4 f = src[cid];
            ushort4v u;
            u[0] = f2bf(f[0]); u[1] = f2bf(f[1]); u[2] = f2bf(f[2]); u[3] = f2bf(f[3]);
            *(ushort4v*)&Xm[row * SK + ch * 4] = u;
        }
        for (int cid = t; cid < 512; cid += 256) {   // zero rows 40..47
            int row = 40 + (cid >> 6), ch = cid & 63;
            ushort4v z = {0, 0, 0, 0};
            *(ushort4v*)&Xm[row * SK + ch * 4] = z;
        }
    } else {
        const int4v* __restrict__ src = (const int4v*)((const u16*)Xv + b * 10240);
        #pragma unroll
        for (int it = 0; it < 6; ++it) {
            int cid = t + it * 256;
            int row = cid >> 5, ch = cid & 31;
            if (cid < 1280) *(int4v*)&Xm[row * SK + ch * 8] = src[cid];
            else if (cid < 1536) { int4v z = {0, 0, 0, 0}; *(int4v*)&Xm[row * SK + ch * 8] = z; }
        }
    }
    // Wb2[256][5] -> WsB[c][k] bf16, c<16 (rows 5..15 zero)
    #pragma unroll
    for (int it = 0; it < 16; ++it) {
        int e2 = t + it * 256;                // < 4096
        int c = e2 >> 8, k = e2 & 255;
        WsB[c * 264 + k] = (c < 5) ? ldW(Wb2, k * 5 + c, isF32) : (u16)0;
    }

    const int w = t >> 6, l = t & 63;
    const int ml = l & 15, kq = l >> 4, r0 = kq * 4;

    // ---- layer 1: P = X @ Wb1 (+bb1 on P1 half), 8 panels of 64 cols ----
    for (int p = 0; p < 8; ++p) {
        __syncthreads();
        {
            const int4v* __restrict__ src =
                (const int4v*)(WallT + (512 + p * 64) * 256);
            #pragma unroll
            for (int it = 0; it < 8; ++it) {
                int c2 = t + it * 256;
                int row = c2 >> 5, ch = c2 & 31;
                *(int4v*)&WbL[row * SK + ch * 8] = src[c2];
            }
        }
        __syncthreads();

        floatx4 acc[3] = {};
        #pragma unroll
        for (int ks = 0; ks < 8; ++ks) {
            const int k0 = ks * 32 + kq * 8;
            bf16x8 bf = *(const bf16x8*)&WbL[(w * 16 + ml) * SK + k0];
            #pragma unroll
            for (int i = 0; i < 3; ++i) {
                bf16x8 a = *(const bf16x8*)&Xm[(i * 16 + ml) * SK + k0];
                acc[i] = __builtin_amdgcn_mfma_f32_16x16x32_bf16(a, bf, acc[i], 0, 0, 0);
            }
        }
        const int gc = p * 64 + w * 16 + ml;
        u16* dst = (gc < 256) ? P1L : P2L;
        const int col = gc & 255;
        const float bias = (gc < 256) ? biasF[512 + gc] : 0.f;   // bb1 on P1
        #pragma unroll
        for (int i = 0; i < 3; ++i)
            #pragma unroll
            for (int r = 0; r < 4; ++r)
                dst[(i * 16 + r0 + r) * SK + col] = f2bf(acc[i][r] + bias);
    }
    __syncthreads();

    // ---- pair phase (NEW): 120 MFMA tasks (i, jtile); wave does T = w+4n ----
    for (int n = 0; n < 30; ++n) {
        const int T = w + 4 * n;               // < 120
        const int i = T / 3, jt = T - 3 * (T / 3);
        floatx4 acc = {};
        #pragma unroll
        for (int ks = 0; ks < 8; ++ks) {
            const int k0 = ks * 32 + kq * 8;
            uint4v pa = *(const uint4v*)&P1L[i * SK + k0];               // row i (bcast)
            uint4v pb = *(const uint4v*)&P2L[(jt * 16 + ml) * SK + k0];  // rows <=47 ok
            bf16x8 af;
            #pragma unroll
            for (int d = 0; d < 4; ++d) {
                af[2 * d]     = (short)f2bf(lrelu(bfLo(pa[d]) + bfLo(pb[d])));
                af[2 * d + 1] = (short)f2bf(lrelu(bfHi(pa[d]) + bfHi(pb[d])));
            }
            bf16x8 bfr = *(const bf16x8*)&WsB[ml * 264 + k0];
            acc = __builtin_amdgcn_mfma_f32_16x16x32_bf16(af, bfr, acc, 0, 0, 0);
        }
        if (ml < 5) {                          // D: row=kq*4+r (j'), col=ml (class)
            #pragma unroll
            for (int r = 0; r < 4; ++r) {
                const int j = jt * 16 + r0 + r;
                if (j < 40) fbuf[(i * 40 + j) * 5 + ml] = acc[r];
            }
        }
    }
    __syncthreads();

    // ---- phase 2: symmetrize + 2*bb2 + store ----
    const int base = 460800 + b * 8000;
    for (int e = t; e < 8000; e += 256) {
        int pr = e / 5, c = e - pr * 5;
        int i = pr / 40, j = pr - (pr / 40) * 40;
        float v = fbuf[e] + fbuf[(j * 40 + i) * 5 + c] + 2.f * biasF[816 + c];
        if (isF32) ((float*)outv)[base + e] = v;
        else ((__hip_bfloat16*)outv)[base + e] = __float2bfloat16(v);
    }
}

// ---------------------------------------------------------------------------
extern "C" void kernel_launch(void* const* d_in, const int* in_sizes, int n_in,
                              void* d_out, int out_size, void* d_ws, size_t ws_size,
                              hipStream_t stream)
{
    const void* yhat = d_in[0];
    const void* Ws1  = d_in[1];
    const void* bs1  = d_in[2];
    const void* Ws2  = d_in[3];
    const void* bs2  = d_in[4];
    const void* Wc1  = d_in[5];
    const void* bc1  = d_in[6];
    const void* Wc2  = d_in[7];
    const void* bc2  = d_in[8];
    const void* Wb1  = d_in[9];
    const void* bb1  = d_in[10];
    const void* Wb2  = d_in[11];
    const void* bb2  = d_in[12];

    // workspace: 565248 bytes total
    char* wsb = (char*)d_ws;
    int*   flag  = (int*)(wsb + 0);
    float* biasF = (float*)(wsb + 4096);     // 1024 floats
    u16*   W2T   = (u16*)(wsb + 8192);       // 64*256 bf16  = 32768 B
    u16*   WallT = (u16*)(wsb + 40960);      // 1024*256 bf16 = 524288 B

    probe_kernel<<<1, 256, 0, stream>>>((const u16*)yhat, flag);
    pack_kernel<<<1092, 256, 0, stream>>>(flag, Ws1, Wc1, Wb1, Ws2, Wc2,
                                          bs1, bc1, bb1, bs2, bc2, bb2,
                                          WallT, W2T, biasF);
    heads_kernel<<<80, 256, 0, stream>>>(flag, yhat, WallT, W2T, biasF, d_out);
    bonds_kernel<<<256, 256, 0, stream>>>(flag, yhat, WallT, Wb2, biasF, d_out);
}

// Round 7
// 160.697 us; speedup vs baseline: 1.1159x; 1.0828x over previous
//
#include <hip/hip_runtime.h>
#include <hip/hip_bf16.h>

typedef unsigned short u16;
typedef __attribute__((ext_vector_type(4))) int   int4v;
typedef __attribute__((ext_vector_type(4))) unsigned int uint4v;
typedef __attribute__((ext_vector_type(4))) unsigned short ushort4v;
typedef __attribute__((ext_vector_type(4))) float floatx4;
typedef __attribute__((ext_vector_type(8))) short bf16x8;

#define LRELU_NS 0.01f
#define SK 264   // LDS k-stride (bf16): 256 + 8 pad, 16B-aligned rows

__device__ __forceinline__ float bitsToF(unsigned int b) {
    union { unsigned int u; float f; } v; v.u = b << 16; return v.f;
}
__device__ __forceinline__ float bfLo(unsigned int d) {
    union { unsigned int u; float f; } v; v.u = d << 16; return v.f;
}
__device__ __forceinline__ float bfHi(unsigned int d) {
    union { unsigned int u; float f; } v; v.u = d & 0xffff0000u; return v.f;
}
__device__ __forceinline__ u16 f2bf(float f) {
    __hip_bfloat16 h = __float2bfloat16(f);
    return *reinterpret_cast<u16*>(&h);
}
__device__ __forceinline__ float lrelu(float v) {
    return fmaxf(v, 0.f) + LRELU_NS * fminf(v, 0.f);
}
// dtype-adaptive element fetch (isF32 is block-uniform)
__device__ __forceinline__ u16 ldW(const void* p, int i, int isF32) {
    return isF32 ? f2bf(((const float*)p)[i]) : ((const u16*)p)[i];
}
__device__ __forceinline__ float ldF(const void* p, int i, int isF32) {
    return isF32 ? ((const float*)p)[i]
                 : bitsToF((unsigned int)((const u16*)p)[i]);
}

// ---------------------------------------------------------------------------
// Kernel 0: dtype probe (unchanged, verified R3/R6).
// ---------------------------------------------------------------------------
__global__ __launch_bounds__(256) void probe_kernel(
    const u16* __restrict__ y, int* __restrict__ flag)
{
    __shared__ int cnt;
    if (threadIdx.x == 0) cnt = 0;
    __syncthreads();
    u16 v = y[2 * threadIdx.x];
    int e = (v >> 7) & 0xFF;
    if (v == 0 || (e >= 96 && e < 160)) atomicAdd(&cnt, 1);
    __syncthreads();
    if (threadIdx.x == 0) *flag = (cnt < 192) ? 1 : 0;
}

// ---------------------------------------------------------------------------
// Kernel 1: pack — NEW: LDS-tiled transpose (coalesced reads AND writes).
// blocks 0..63: WallT 64x64 tiles; 64..127: W2T; 128..131: biasF.
// Same output layout as R3/R6.
// ---------------------------------------------------------------------------
__global__ __launch_bounds__(256) void pack_kernel(
    const int* __restrict__ flag,
    const void* __restrict__ Ws1, const void* __restrict__ Wc1,
    const void* __restrict__ Wb1, const void* __restrict__ Ws2,
    const void* __restrict__ Wc2,
    const void* __restrict__ bs1, const void* __restrict__ bc1,
    const void* __restrict__ bb1, const void* __restrict__ bs2,
    const void* __restrict__ bc2, const void* __restrict__ bb2,
    u16* __restrict__ WallT, u16* __restrict__ W2T, float* __restrict__ biasF)
{
    const int isF32 = *flag;
    const int bid = blockIdx.x, t = threadIdx.x;
    if (bid < 64) {
        __shared__ u16 tile[64][65];
        const int c0 = (bid & 15) * 64;      // col-tile in [0,1024)
        const int k0 = (bid >> 4) * 64;      // k-tile in [0,256)
        const void* src; int coff; int roff = 0;
        if (c0 < 256)      { src = Ws1; coff = c0; }
        else if (c0 < 512) { src = Wc1; coff = c0 - 256; }
        else if (c0 < 768) { src = Wb1; coff = c0 - 512; }
        else               { src = Wb1; coff = c0 - 768; roff = 256; }
        const int cc = t & 63, kk0 = t >> 6;
        #pragma unroll
        for (int i = 0; i < 16; ++i) {
            int kk = kk0 + i * 4;
            tile[kk][cc] = ldW(src, (k0 + kk + roff) * 256 + coff + cc, isF32);
        }
        __syncthreads();
        const int kk2 = t & 63, cc0 = t >> 6;
        #pragma unroll
        for (int i = 0; i < 16; ++i) {
            int cc2 = cc0 + i * 4;
            WallT[(c0 + cc2) * 256 + (k0 + kk2)] = tile[kk2][cc2];
        }
    } else if (bid < 128) {
        int e2 = (bid - 64) * 256 + t;       // < 16384
        int c = e2 >> 8, k = e2 & 255;
        u16 v = 0;
        if (c < 40)                 v = ldW(Ws2, k * 40 + c, isF32);
        else if (c >= 48 && c < 53) v = ldW(Wc2, k * 5 + (c - 48), isF32);
        W2T[c * 256 + k] = v;
    } else {
        int idx = (bid - 128) * 256 + t;     // < 1024
        float v = 0.f;
        if (idx < 256)       v = ldF(bs1, idx, isF32);
        else if (idx < 512)  v = ldF(bc1, idx - 256, isF32);
        else if (idx < 768)  v = ldF(bb1, idx - 512, isF32);
        else if (idx < 808)  v = ldF(bs2, idx - 768, isF32);
        else if (idx < 813)  v = ldF(bc2, idx - 808, isF32);
        else if (idx >= 816 && idx < 821) v = ldF(bb2, idx - 816, isF32);
        biasF[idx] = v;
    }
}

// ---------------------------------------------------------------------------
// Kernel 2: symbols + charges — R6 body; ONLY delta: head = blockIdx.y
// (grid 80x2), layer-2 loops manually unrolled with uniform guards.
// LDS: Xs 67584 + Wb 16896 + Hb 67584 = 152064 B.
// ---------------------------------------------------------------------------
__global__ __launch_bounds__(256) void heads_kernel(
    const int* __restrict__ flag,
    const void* __restrict__ Xv, const u16* __restrict__ WallT,
    const u16* __restrict__ W2T, const float* __restrict__ biasF,
    void* __restrict__ outv)
{
    __shared__ u16 Xs[128 * SK];
    __shared__ u16 Wb[32 * SK];
    __shared__ u16 Hb[128 * SK];
    const int t = threadIdx.x;
    const int bm0 = blockIdx.x * 128;
    const int head = blockIdx.y;
    const int isF32 = *flag;

    if (isF32) {   // stage X tile [128][256] from fp32, cvt to bf16
        const floatx4* __restrict__ src = (const floatx4*)((const float*)Xv + bm0 * 256);
        #pragma unroll
        for (int it = 0; it < 32; ++it) {
            int cid = t + it * 256;
            int row = cid >> 6, ch = cid & 63;
            floatx4 f = src[cid];
            ushort4v u;
            u[0] = f2bf(f[0]); u[1] = f2bf(f[1]); u[2] = f2bf(f[2]); u[3] = f2bf(f[3]);
            *(ushort4v*)&Xs[row * SK + ch * 4] = u;
        }
    } else {       // stage X tile from bf16
        const int4v* __restrict__ src = (const int4v*)((const u16*)Xv + bm0 * 256);
        #pragma unroll
        for (int it = 0; it < 16; ++it) {
            int cid = t + it * 256;
            int row = cid >> 5, ch = cid & 31;
            *(int4v*)&Xs[row * SK + ch * 8] = src[cid];
        }
    }

    const int w = t >> 6, l = t & 63;
    const int ml = l & 15, kq = l >> 4, r0 = kq * 4;

    // ---- layer 1: 8 panels of 32 H-columns ----
    for (int p = 0; p < 8; ++p) {
        __syncthreads();   // prev panel's Wb reads done / Xs visible (p=0)
        {
            const int4v* __restrict__ src =
                (const int4v*)(WallT + (head * 256 + p * 32) * 256);
            #pragma unroll
            for (int it = 0; it < 4; ++it) {
                int c2 = t + it * 256;
                int row = c2 >> 5, ch = c2 & 31;
                *(int4v*)&Wb[row * SK + ch * 8] = src[c2];
            }
        }
        __syncthreads();

        floatx4 acc[2][2] = {};
        #pragma unroll
        for (int ks = 0; ks < 8; ++ks) {
            const int k0 = ks * 32 + kq * 8;
            bf16x8 a[2], bf[2];
            a[0]  = *(const bf16x8*)&Xs[(w * 32 + ml) * SK + k0];
            a[1]  = *(const bf16x8*)&Xs[(w * 32 + 16 + ml) * SK + k0];
            bf[0] = *(const bf16x8*)&Wb[(ml) * SK + k0];
            bf[1] = *(const bf16x8*)&Wb[(16 + ml) * SK + k0];
            #pragma unroll
            for (int i = 0; i < 2; ++i)
                #pragma unroll
                for (int j = 0; j < 2; ++j)
                    acc[i][j] = __builtin_amdgcn_mfma_f32_16x16x32_bf16(
                        a[i], bf[j], acc[i][j], 0, 0, 0);
        }
        #pragma unroll
        for (int j = 0; j < 2; ++j) {
            const int hcol = p * 32 + j * 16 + ml;
            const float bias = biasF[head * 256 + hcol];  // bs1 | bc1
            #pragma unroll
            for (int i = 0; i < 2; ++i)
                #pragma unroll
                for (int r = 0; r < 4; ++r) {
                    const int row = w * 32 + i * 16 + r0 + r;
                    Hb[row * SK + hcol] = f2bf(lrelu(acc[i][j][r] + bias));
                }
        }
    }
    __syncthreads();   // Hb complete

    // ---- layer 2: H[128,256] @ W2[256, 40|5] ----
    const int nct = (head == 0) ? 3 : 1;    // block-uniform
    const int c0  = (head == 0) ? 0 : 48;
    floatx4 acc2[2][3] = {};
    #pragma unroll
    for (int ks = 0; ks < 8; ++ks) {
        const int k0 = ks * 32 + kq * 8;
        bf16x8 a[2];
        a[0] = *(const bf16x8*)&Hb[(w * 32 + ml) * SK + k0];
        a[1] = *(const bf16x8*)&Hb[(w * 32 + 16 + ml) * SK + k0];
        #pragma unroll
        for (int j = 0; j < 3; ++j) {
            if (j < nct) {
                bf16x8 bf = *(const bf16x8*)&W2T[(c0 + j * 16 + ml) * 256 + k0];
                #pragma unroll
                for (int i = 0; i < 2; ++i)
                    acc2[i][j] = __builtin_amdgcn_mfma_f32_16x16x32_bf16(
                        a[i], bf, acc2[i][j], 0, 0, 0);
            }
        }
    }
    #pragma unroll
    for (int j = 0; j < 3; ++j) {
        if (j < nct) {
            const int col = j * 16 + ml;
            const int lim = (head == 0) ? 40 : 5;
            if (col < lim) {
                const float bias = biasF[(head == 0 ? 768 : 808) + col];
                #pragma unroll
                for (int i = 0; i < 2; ++i)
                    #pragma unroll
                    for (int r = 0; r < 4; ++r) {
                        const int row = bm0 + w * 32 + i * 16 + r0 + r;
                        const int o = (head == 0) ? row * 40 + col
                                                  : 409600 + row * 5 + col;
                        const float v = acc2[i][j][r] + bias;
                        if (isF32) ((float*)outv)[o] = v;
                        else ((__hip_bfloat16*)outv)[o] = __float2bfloat16(v);
                    }
            }
        }
    }
}

// ---------------------------------------------------------------------------
// Kernel 3: bonds — R6 body; ONLY delta: layer-1 B-frags read directly from
// global WallT (WbL + its 16 barriers deleted).
// LDS: Xm 25344 + P1L 25344 + P2L 25344 + WsB 8448 + fbuf 32000 = 116480 B.
// ---------------------------------------------------------------------------
__global__ __launch_bounds__(256) void bonds_kernel(
    const int* __restrict__ flag,
    const void* __restrict__ Xv, const u16* __restrict__ WallT,
    const void* __restrict__ Wb2, const float* __restrict__ biasF,
    void* __restrict__ outv)
{
    __shared__ u16 Xm[48 * SK];
    __shared__ u16 P1L[48 * SK];
    __shared__ u16 P2L[48 * SK];
    __shared__ u16 WsB[16 * 264];
    __shared__ float fbuf[8000];
    const int t = threadIdx.x, b = blockIdx.x;
    const int isF32 = *flag;

    if (isF32) {   // stage X rows 0..39 (fp32 -> bf16), zero rows 40..47
        const floatx4* __restrict__ src = (const floatx4*)((const float*)Xv + b * 10240);
        #pragma unroll
        for (int it = 0; it < 10; ++it) {
            int cid = t + it * 256;
            int row = cid >> 6, ch = cid & 63;
            floatx4 f = src[cid];
            ushort4v u;
            u[0] = f2bf(f[0]); u[1] = f2bf(f[1]); u[2] = f2bf(f[2]); u[3] = f2bf(f[3]);
            *(ushort4v*)&Xm[row * SK + ch * 4] = u;
        }
        for (int cid = t; cid < 512; cid += 256) {   // zero rows 40..47
            int row = 40 + (cid >> 6), ch = cid & 63;
            ushort4v z = {0, 0, 0, 0};
            *(ushort4v*)&Xm[row * SK + ch * 4] = z;
        }
    } else {
        const int4v* __restrict__ src = (const int4v*)((const u16*)Xv + b * 10240);
        #pragma unroll
        for (int it = 0; it < 6; ++it) {
            int cid = t + it * 256;
            int row = cid >> 5, ch = cid & 31;
            if (cid < 1280) *(int4v*)&Xm[row * SK + ch * 8] = src[cid];
            else if (cid < 1536) { int4v z = {0, 0, 0, 0}; *(int4v*)&Xm[row * SK + ch * 8] = z; }
        }
    }
    // Wb2[256][5] -> WsB[c][k] bf16, c<16 (rows 5..15 zero)
    #pragma unroll
    for (int it = 0; it < 16; ++it) {
        int e2 = t + it * 256;                // < 4096
        int c = e2 >> 8, k = e2 & 255;
        WsB[c * 264 + k] = (c < 5) ? ldW(Wb2, k * 5 + c, isF32) : (u16)0;
    }
    __syncthreads();   // Xm + WsB visible

    const int w = t >> 6, l = t & 63;
    const int ml = l & 15, kq = l >> 4, r0 = kq * 4;

    // ---- layer 1: P = X @ Wb1 (+bb1 on P1 half), B-frags from global ----
    for (int p = 0; p < 8; ++p) {
        const int gc = p * 64 + w * 16 + ml;       // [0,512)
        floatx4 acc[3] = {};
        #pragma unroll
        for (int ks = 0; ks < 8; ++ks) {
            const int k0 = ks * 32 + kq * 8;
            bf16x8 bf = *(const bf16x8*)&WallT[(512 + gc) * 256 + k0];
            #pragma unroll
            for (int i = 0; i < 3; ++i) {
                bf16x8 a = *(const bf16x8*)&Xm[(i * 16 + ml) * SK + k0];
                acc[i] = __builtin_amdgcn_mfma_f32_16x16x32_bf16(a, bf, acc[i], 0, 0, 0);
            }
        }
        u16* dst = (gc < 256) ? P1L : P2L;
        const int col = gc & 255;
        const float bias = (gc < 256) ? biasF[512 + gc] : 0.f;   // bb1 on P1
        #pragma unroll
        for (int i = 0; i < 3; ++i)
            #pragma unroll
            for (int r = 0; r < 4; ++r)
                dst[(i * 16 + r0 + r) * SK + col] = f2bf(acc[i][r] + bias);
    }
    __syncthreads();

    // ---- pair phase: 120 MFMA tasks (i, jtile); wave does T = w+4n ----
    for (int n = 0; n < 30; ++n) {
        const int T = w + 4 * n;               // < 120
        const int i = T / 3, jt = T - 3 * (T / 3);
        floatx4 acc = {};
        #pragma unroll
        for (int ks = 0; ks < 8; ++ks) {
            const int k0 = ks * 32 + kq * 8;
            uint4v pa = *(const uint4v*)&P1L[i * SK + k0];               // row i (bcast)
            uint4v pb = *(const uint4v*)&P2L[(jt * 16 + ml) * SK + k0];  // rows <=47 ok
            bf16x8 af;
            #pragma unroll
            for (int d = 0; d < 4; ++d) {
                af[2 * d]     = (short)f2bf(lrelu(bfLo(pa[d]) + bfLo(pb[d])));
                af[2 * d + 1] = (short)f2bf(lrelu(bfHi(pa[d]) + bfHi(pb[d])));
            }
            bf16x8 bfr = *(const bf16x8*)&WsB[ml * 264 + k0];
            acc = __builtin_amdgcn_mfma_f32_16x16x32_bf16(af, bfr, acc, 0, 0, 0);
        }
        if (ml < 5) {                          // D: row=kq*4+r (j'), col=ml (class)
            #pragma unroll
            for (int r = 0; r < 4; ++r) {
                const int j = jt * 16 + r0 + r;
                if (j < 40) fbuf[(i * 40 + j) * 5 + ml] = acc[r];
            }
        }
    }
    __syncthreads();

    // ---- phase 2: symmetrize + 2*bb2 + store ----
    const int base = 460800 + b * 8000;
    for (int e = t; e < 8000; e += 256) {
        int pr = e / 5, c = e - pr * 5;
        int i = pr / 40, j = pr - (pr / 40) * 40;
        float v = fbuf[e] + fbuf[(j * 40 + i) * 5 + c] + 2.f * biasF[816 + c];
        if (isF32) ((float*)outv)[base + e] = v;
        else ((__hip_bfloat16*)outv)[base + e] = __float2bfloat16(v);
    }
}

// ---------------------------------------------------------------------------
extern "C" void kernel_launch(void* const* d_in, const int* in_sizes, int n_in,
                              void* d_out, int out_size, void* d_ws, size_t ws_size,
                              hipStream_t stream)
{
    const void* yhat = d_in[0];
    const void* Ws1  = d_in[1];
    const void* bs1  = d_in[2];
    const void* Ws2  = d_in[3];
    const void* bs2  = d_in[4];
    const void* Wc1  = d_in[5];
    const void* bc1  = d_in[6];
    const void* Wc2  = d_in[7];
    const void* bc2  = d_in[8];
    const void* Wb1  = d_in[9];
    const void* bb1  = d_in[10];
    const void* Wb2  = d_in[11];
    const void* bb2  = d_in[12];

    // workspace: 565248 bytes total
    char* wsb = (char*)d_ws;
    int*   flag  = (int*)(wsb + 0);
    float* biasF = (float*)(wsb + 4096);     // 1024 floats
    u16*   W2T   = (u16*)(wsb + 8192);       // 64*256 bf16  = 32768 B
    u16*   WallT = (u16*)(wsb + 40960);      // 1024*256 bf16 = 524288 B

    probe_kernel<<<1, 256, 0, stream>>>((const u16*)yhat, flag);
    pack_kernel<<<132, 256, 0, stream>>>(flag, Ws1, Wc1, Wb1, Ws2, Wc2,
                                         bs1, bc1, bb1, bs2, bc2, bb2,
                                         WallT, W2T, biasF);
    heads_kernel<<<dim3(80, 2), 256, 0, stream>>>(flag, yhat, WallT, W2T, biasF, d_out);
    bonds_kernel<<<256, 256, 0, stream>>>(flag, yhat, WallT, Wb2, biasF, d_out);
}

// Round 8
// 140.366 us; speedup vs baseline: 1.2775x; 1.1448x over previous
//
#include <hip/hip_runtime.h>
#include <hip/hip_bf16.h>

typedef unsigned short u16;
typedef __attribute__((ext_vector_type(4))) int   int4v;
typedef __attribute__((ext_vector_type(4))) unsigned int uint4v;
typedef __attribute__((ext_vector_type(4))) unsigned short ushort4v;
typedef __attribute__((ext_vector_type(4))) float floatx4;
typedef __attribute__((ext_vector_type(8))) short bf16x8;

#define LRELU_NS 0.01f
#define SK 264   // LDS k-stride (bf16): 256 + 8 pad, 16B-aligned rows

__device__ __forceinline__ float bitsToF(unsigned int b) {
    union { unsigned int u; float f; } v; v.u = b << 16; return v.f;
}
__device__ __forceinline__ float bfLo(unsigned int d) {
    union { unsigned int u; float f; } v; v.u = d << 16; return v.f;
}
__device__ __forceinline__ float bfHi(unsigned int d) {
    union { unsigned int u; float f; } v; v.u = d & 0xffff0000u; return v.f;
}
__device__ __forceinline__ u16 f2bf(float f) {
    __hip_bfloat16 h = __float2bfloat16(f);
    return *reinterpret_cast<u16*>(&h);
}
__device__ __forceinline__ float lrelu(float v) {
    return fmaxf(v, 0.f) + LRELU_NS * fminf(v, 0.f);
}
// dtype-adaptive element fetch (isF32 is block-uniform)
__device__ __forceinline__ u16 ldW(const void* p, int i, int isF32) {
    return isF32 ? f2bf(((const float*)p)[i]) : ((const u16*)p)[i];
}
__device__ __forceinline__ float ldF(const void* p, int i, int isF32) {
    return isF32 ? ((const float*)p)[i]
                 : bitsToF((unsigned int)((const u16*)p)[i]);
}

// ---------------------------------------------------------------------------
// Inlined dtype probe (logic identical to verified R3/R6/R7 probe_kernel).
// Must be called unconditionally by all threads of the block.
// ---------------------------------------------------------------------------
__device__ __forceinline__ int computeIsF32(const u16* y, int* cnt, int t) {
    if (t == 0) *cnt = 0;
    __syncthreads();
    if (t < 256) {
        u16 v = y[2 * t];
        int e = (v >> 7) & 0xFF;
        if (v == 0 || (e >= 96 && e < 160)) atomicAdd(cnt, 1);
    }
    __syncthreads();
    return (*cnt < 192) ? 1 : 0;
}

// ---------------------------------------------------------------------------
// Kernel 1: pack — R7 body (verified); delta: flag computed in-block from
// yhat instead of workspace read (probe kernel deleted).
// blocks 0..63: WallT 64x64 transpose tiles; 64..127: W2T; 128..131: biasF.
// ---------------------------------------------------------------------------
__global__ __launch_bounds__(256) void pack_kernel(
    const void* __restrict__ yhat,
    const void* __restrict__ Ws1, const void* __restrict__ Wc1,
    const void* __restrict__ Wb1, const void* __restrict__ Ws2,
    const void* __restrict__ Wc2,
    const void* __restrict__ bs1, const void* __restrict__ bc1,
    const void* __restrict__ bb1, const void* __restrict__ bs2,
    const void* __restrict__ bc2, const void* __restrict__ bb2,
    u16* __restrict__ WallT, u16* __restrict__ W2T, float* __restrict__ biasF)
{
    __shared__ int fcnt;
    const int bid = blockIdx.x, t = threadIdx.x;
    const int isF32 = computeIsF32((const u16*)yhat, &fcnt, t);
    if (bid < 64) {
        __shared__ u16 tile[64][65];
        const int c0 = (bid & 15) * 64;      // col-tile in [0,1024)
        const int k0 = (bid >> 4) * 64;      // k-tile in [0,256)
        const void* src; int coff; int roff = 0;
        if (c0 < 256)      { src = Ws1; coff = c0; }
        else if (c0 < 512) { src = Wc1; coff = c0 - 256; }
        else if (c0 < 768) { src = Wb1; coff = c0 - 512; }
        else               { src = Wb1; coff = c0 - 768; roff = 256; }
        const int cc = t & 63, kk0 = t >> 6;
        #pragma unroll
        for (int i = 0; i < 16; ++i) {
            int kk = kk0 + i * 4;
            tile[kk][cc] = ldW(src, (k0 + kk + roff) * 256 + coff + cc, isF32);
        }
        __syncthreads();
        const int kk2 = t & 63, cc0 = t >> 6;
        #pragma unroll
        for (int i = 0; i < 16; ++i) {
            int cc2 = cc0 + i * 4;
            WallT[(c0 + cc2) * 256 + (k0 + kk2)] = tile[kk2][cc2];
        }
    } else if (bid < 128) {
        int e2 = (bid - 64) * 256 + t;       // < 16384
        int c = e2 >> 8, k = e2 & 255;
        u16 v = 0;
        if (c < 40)                 v = ldW(Ws2, k * 40 + c, isF32);
        else if (c >= 48 && c < 53) v = ldW(Wc2, k * 5 + (c - 48), isF32);
        W2T[c * 256 + k] = v;
    } else {
        int idx = (bid - 128) * 256 + t;     // < 1024
        float v = 0.f;
        if (idx < 256)       v = ldF(bs1, idx, isF32);
        else if (idx < 512)  v = ldF(bc1, idx - 256, isF32);
        else if (idx < 768)  v = ldF(bb1, idx - 512, isF32);
        else if (idx < 808)  v = ldF(bs2, idx - 768, isF32);
        else if (idx < 813)  v = ldF(bc2, idx - 808, isF32);
        else if (idx >= 816 && idx < 821) v = ldF(bb2, idx - 816, isF32);
        biasF[idx] = v;
    }
}

// ---------------------------------------------------------------------------
// Kernel 2: symbols + charges — restructured from verified parts only.
// 64-atom blocks, grid (160, 2), head = blockIdx.y. Layer-1 B-frags read
// directly from global WallT (pattern verified in bonds L1 / heads L2).
// LDS: Xs 33792 + Hb 33792 = 67584 B -> 2 blocks/CU. 2 barriers (+2 probe).
// ---------------------------------------------------------------------------
__global__ __launch_bounds__(256) void heads_kernel(
    const void* __restrict__ Xv, const u16* __restrict__ WallT,
    const u16* __restrict__ W2T, const float* __restrict__ biasF,
    void* __restrict__ outv)
{
    __shared__ u16 Xs[64 * SK];
    __shared__ u16 Hb[64 * SK];
    __shared__ int fcnt;
    const int t = threadIdx.x;
    const int bm0 = blockIdx.x * 64;
    const int head = blockIdx.y;
    const int isF32 = computeIsF32((const u16*)Xv, &fcnt, t);

    if (isF32) {   // stage X tile [64][256] from fp32, cvt to bf16
        const floatx4* __restrict__ src = (const floatx4*)((const float*)Xv + bm0 * 256);
        #pragma unroll
        for (int it = 0; it < 16; ++it) {
            int cid = t + it * 256;            // 4096 chunks of 4 floats
            int row = cid >> 6, ch = cid & 63;
            floatx4 f = src[cid];
            ushort4v u;
            u[0] = f2bf(f[0]); u[1] = f2bf(f[1]); u[2] = f2bf(f[2]); u[3] = f2bf(f[3]);
            *(ushort4v*)&Xs[row * SK + ch * 4] = u;
        }
    } else {       // stage X tile from bf16
        const int4v* __restrict__ src = (const int4v*)((const u16*)Xv + bm0 * 256);
        #pragma unroll
        for (int it = 0; it < 8; ++it) {
            int cid = t + it * 256;            // 2048 chunks of 8 bf16
            int row = cid >> 5, ch = cid & 31;
            *(int4v*)&Xs[row * SK + ch * 8] = src[cid];
        }
    }
    __syncthreads();

    const int w = t >> 6, l = t & 63;
    const int ml = l & 15, kq = l >> 4, r0 = kq * 4;

    // ---- layer 1: 16 col-tiles; wave does ct = w+4n; 4 M-tiles each ----
    for (int n = 0; n < 4; ++n) {
        const int ct = w + 4 * n;
        floatx4 acc[4] = {};
        #pragma unroll
        for (int ks = 0; ks < 8; ++ks) {
            const int k0 = ks * 32 + kq * 8;
            bf16x8 bf = *(const bf16x8*)&WallT[(head * 256 + ct * 16 + ml) * 256 + k0];
            #pragma unroll
            for (int mt = 0; mt < 4; ++mt) {
                bf16x8 a = *(const bf16x8*)&Xs[(mt * 16 + ml) * SK + k0];
                acc[mt] = __builtin_amdgcn_mfma_f32_16x16x32_bf16(a, bf, acc[mt], 0, 0, 0);
            }
        }
        const int col = ct * 16 + ml;          // [0,256)
        const float bias = biasF[head * 256 + col];   // bs1 | bc1
        #pragma unroll
        for (int mt = 0; mt < 4; ++mt)
            #pragma unroll
            for (int r = 0; r < 4; ++r)
                Hb[(mt * 16 + r0 + r) * SK + col] = f2bf(lrelu(acc[mt][r] + bias));
    }
    __syncthreads();   // Hb complete

    // ---- layer 2: wave w owns M-tile mt = w ----
    const int nct = (head == 0) ? 3 : 1;       // block-uniform
    const int c0  = (head == 0) ? 0 : 48;
    floatx4 acc2[3] = {};
    #pragma unroll
    for (int ks = 0; ks < 8; ++ks) {
        const int k0 = ks * 32 + kq * 8;
        bf16x8 a = *(const bf16x8*)&Hb[(w * 16 + ml) * SK + k0];
        #pragma unroll
        for (int j = 0; j < 3; ++j) {
            if (j < nct) {
                bf16x8 bf = *(const bf16x8*)&W2T[(c0 + j * 16 + ml) * 256 + k0];
                acc2[j] = __builtin_amdgcn_mfma_f32_16x16x32_bf16(a, bf, acc2[j], 0, 0, 0);
            }
        }
    }
    #pragma unroll
    for (int j = 0; j < 3; ++j) {
        if (j < nct) {
            const int col = j * 16 + ml;
            const int lim = (head == 0) ? 40 : 5;
            if (col < lim) {
                const float bias = biasF[(head == 0 ? 768 : 808) + col];
                #pragma unroll
                for (int r = 0; r < 4; ++r) {
                    const int row = bm0 + w * 16 + r0 + r;
                    const int o = (head == 0) ? row * 40 + col
                                              : 409600 + row * 5 + col;
                    const float v = acc2[j][r] + bias;
                    if (isF32) ((float*)outv)[o] = v;
                    else ((__hip_bfloat16*)outv)[o] = __float2bfloat16(v);
                }
            }
        }
    }
}

// ---------------------------------------------------------------------------
// Kernel 3: bonds — R7 algorithm; deltas: 512 threads (8 waves -> 2/SIMD),
// pair phase regrouped per-i with pa/Wb2 fragments hoisted to registers
// (LDS b128 reads per block 2880 -> 1344). Math and D-mapping unchanged.
// LDS: Xm 25344 + P1L 25344 + P2L 25344 + WsB 8448 + fbuf 32000 = 116480 B.
// ---------------------------------------------------------------------------
__global__ __launch_bounds__(512) void bonds_kernel(
    const void* __restrict__ Xv, const u16* __restrict__ WallT,
    const void* __restrict__ Wb2, const float* __restrict__ biasF,
    void* __restrict__ outv)
{
    __shared__ u16 Xm[48 * SK];
    __shared__ u16 P1L[48 * SK];
    __shared__ u16 P2L[48 * SK];
    __shared__ u16 WsB[16 * 264];
    __shared__ float fbuf[8000];
    __shared__ int fcnt;
    const int t = threadIdx.x, b = blockIdx.x;
    const int isF32 = computeIsF32((const u16*)Xv, &fcnt, t);

    if (isF32) {   // stage X rows 0..39 (fp32 -> bf16), zero rows 40..47
        const floatx4* __restrict__ src = (const floatx4*)((const float*)Xv + b * 10240);
        #pragma unroll
        for (int it = 0; it < 5; ++it) {
            int cid = t + it * 512;            // 2560 chunks of 4 floats
            int row = cid >> 6, ch = cid & 63;
            floatx4 f = src[cid];
            ushort4v u;
            u[0] = f2bf(f[0]); u[1] = f2bf(f[1]); u[2] = f2bf(f[2]); u[3] = f2bf(f[3]);
            *(ushort4v*)&Xm[row * SK + ch * 4] = u;
        }
        {   // zero rows 40..47 (512 ushort4 chunks)
            int row = 40 + (t >> 6), ch = t & 63;
            ushort4v z = {0, 0, 0, 0};
            *(ushort4v*)&Xm[row * SK + ch * 4] = z;
        }
    } else {
        const int4v* __restrict__ src = (const int4v*)((const u16*)Xv + b * 10240);
        #pragma unroll
        for (int it = 0; it < 3; ++it) {
            int cid = t + it * 512;            // < 1536
            int row = cid >> 5, ch = cid & 31;
            if (cid < 1280) *(int4v*)&Xm[row * SK + ch * 8] = src[cid];
            else { int4v z = {0, 0, 0, 0}; *(int4v*)&Xm[row * SK + ch * 8] = z; }
        }
    }
    // Wb2[256][5] -> WsB[c][k] bf16, c<16 (rows 5..15 zero)
    #pragma unroll
    for (int it = 0; it < 8; ++it) {
        int e2 = t + it * 512;                 // < 4096
        int c = e2 >> 8, k = e2 & 255;
        WsB[c * 264 + k] = (c < 5) ? ldW(Wb2, k * 5 + c, isF32) : (u16)0;
    }
    __syncthreads();   // Xm + WsB visible

    const int w = t >> 6, l = t & 63;          // w in [0,8)
    const int ml = l & 15, kq = l >> 4, r0 = kq * 4;

    // ---- layer 1: P = X @ Wb1 (+bb1 on P1 half), B-frags from global ----
    for (int n = 0; n < 4; ++n) {
        const int gc = (w + 8 * n) * 16 + ml;  // [0,512), unique per (w,n,ml)
        floatx4 acc[3] = {};
        #pragma unroll
        for (int ks = 0; ks < 8; ++ks) {
            const int k0 = ks * 32 + kq * 8;
            bf16x8 bf = *(const bf16x8*)&WallT[(512 + gc) * 256 + k0];
            #pragma unroll
            for (int i = 0; i < 3; ++i) {
                bf16x8 a = *(const bf16x8*)&Xm[(i * 16 + ml) * SK + k0];
                acc[i] = __builtin_amdgcn_mfma_f32_16x16x32_bf16(a, bf, acc[i], 0, 0, 0);
            }
        }
        u16* dst = (gc < 256) ? P1L : P2L;
        const int col = gc & 255;
        const float bias = (gc < 256) ? biasF[512 + gc] : 0.f;   // bb1 on P1
        #pragma unroll
        for (int i = 0; i < 3; ++i)
            #pragma unroll
            for (int r = 0; r < 4; ++r)
                dst[(i * 16 + r0 + r) * SK + col] = f2bf(acc[i][r] + bias);
    }
    __syncthreads();

    // ---- pair phase: wave w owns i = w + 8m (m<5); 3 j-tiles per i ----
    bf16x8 wf[8];
    #pragma unroll
    for (int ks = 0; ks < 8; ++ks)
        wf[ks] = *(const bf16x8*)&WsB[ml * 264 + ks * 32 + kq * 8];

    for (int m = 0; m < 5; ++m) {
        const int i = w + 8 * m;               // [0,40), unique coverage
        uint4v pa8[8];
        #pragma unroll
        for (int ks = 0; ks < 8; ++ks)
            pa8[ks] = *(const uint4v*)&P1L[i * SK + ks * 32 + kq * 8];
        for (int jt = 0; jt < 3; ++jt) {
            floatx4 acc = {};
            #pragma unroll
            for (int ks = 0; ks < 8; ++ks) {
                const int k0 = ks * 32 + kq * 8;
                uint4v pa = pa8[ks];
                uint4v pb = *(const uint4v*)&P2L[(jt * 16 + ml) * SK + k0];
                bf16x8 af;
                #pragma unroll
                for (int d = 0; d < 4; ++d) {
                    af[2 * d]     = (short)f2bf(lrelu(bfLo(pa[d]) + bfLo(pb[d])));
                    af[2 * d + 1] = (short)f2bf(lrelu(bfHi(pa[d]) + bfHi(pb[d])));
                }
                acc = __builtin_amdgcn_mfma_f32_16x16x32_bf16(af, wf[ks], acc, 0, 0, 0);
            }
            if (ml < 5) {                      // D: row=kq*4+r (j'), col=ml (class)
                #pragma unroll
                for (int r = 0; r < 4; ++r) {
                    const int j = jt * 16 + r0 + r;
                    if (j < 40) fbuf[(i * 40 + j) * 5 + ml] = acc[r];
                }
            }
        }
    }
    __syncthreads();

    // ---- phase 2: symmetrize + 2*bb2 + store ----
    const int base = 460800 + b * 8000;
    for (int e = t; e < 8000; e += 512) {
        int pr = e / 5, c = e - pr * 5;
        int i = pr / 40, j = pr - (pr / 40) * 40;
        float v = fbuf[e] + fbuf[(j * 40 + i) * 5 + c] + 2.f * biasF[816 + c];
        if (isF32) ((float*)outv)[base + e] = v;
        else ((__hip_bfloat16*)outv)[base + e] = __float2bfloat16(v);
    }
}

// ---------------------------------------------------------------------------
extern "C" void kernel_launch(void* const* d_in, const int* in_sizes, int n_in,
                              void* d_out, int out_size, void* d_ws, size_t ws_size,
                              hipStream_t stream)
{
    const void* yhat = d_in[0];
    const void* Ws1  = d_in[1];
    const void* bs1  = d_in[2];
    const void* Ws2  = d_in[3];
    const void* bs2  = d_in[4];
    const void* Wc1  = d_in[5];
    const void* bc1  = d_in[6];
    const void* Wc2  = d_in[7];
    const void* bc2  = d_in[8];
    const void* Wb1  = d_in[9];
    const void* bb1  = d_in[10];
    const void* Wb2  = d_in[11];
    const void* bb2  = d_in[12];

    // workspace: 565248 bytes total
    char* wsb = (char*)d_ws;
    float* biasF = (float*)(wsb + 4096);     // 1024 floats
    u16*   W2T   = (u16*)(wsb + 8192);       // 64*256 bf16  = 32768 B
    u16*   WallT = (u16*)(wsb + 40960);      // 1024*256 bf16 = 524288 B

    pack_kernel<<<132, 256, 0, stream>>>(yhat, Ws1, Wc1, Wb1, Ws2, Wc2,
                                         bs1, bc1, bb1, bs2, bc2, bb2,
                                         WallT, W2T, biasF);
    heads_kernel<<<dim3(160, 2), 256, 0, stream>>>(yhat, WallT, W2T, biasF, d_out);
    bonds_kernel<<<256, 512, 0, stream>>>(yhat, WallT, Wb2, biasF, d_out);
}